// Round 9
// baseline (175.723 us; speedup 1.0000x reference)
//
#include <hip/hip_runtime.h>

typedef __attribute__((ext_vector_type(8))) short bf16x8;
typedef __attribute__((ext_vector_type(4))) float f32x4;

// RNE bf16 (epilogues — off critical path)
__device__ __forceinline__ unsigned short f2bf(float f) {
    unsigned int u = __builtin_bit_cast(unsigned int, f);
    unsigned int r = (u + 0x7FFFu + ((u >> 16) & 1u)) >> 16;
    return (unsigned short)r;
}
// round-half-up pack of two fp32 -> packed bf16x2 (cheap) — streaming hot path
__device__ __forceinline__ unsigned int pkbf(float lo, float hi) {
    unsigned int ul = __builtin_bit_cast(unsigned int, lo) + 0x8000u;
    unsigned int uh = __builtin_bit_cast(unsigned int, hi) + 0x8000u;
    return (uh & 0xFFFF0000u) | (ul >> 16);
}
__device__ __forceinline__ float bf2f(unsigned short u) {
    unsigned int x = ((unsigned int)u) << 16;
    return __builtin_bit_cast(float, x);
}

__device__ __forceinline__ void gll16(const void* g, void* l) {
    __builtin_amdgcn_global_load_lds(
        (const __attribute__((address_space(1))) void*)g,
        (__attribute__((address_space(3))) void*)l, 16, 0, 0);
}

// ---------------------------------------------------------------------------
// kW: tiled transpose + fp32->bf16. src [b][R][C] f32 -> dstT [b][C][R] bf16.
// ---------------------------------------------------------------------------
__global__ __launch_bounds__(256) void transpose_cvt_kernel(
    const float* __restrict__ src, unsigned short* __restrict__ dstT,
    unsigned short* __restrict__ dstS, int R, int C)
{
    __shared__ float tile[64][65];
    const int b = blockIdx.z;
    const float* s = src + (size_t)b * R * C;
    const int r0 = blockIdx.x * 64, c0 = blockIdx.y * 64;
    const int t = threadIdx.x;
    const int r = t >> 2, cg = (t & 3) * 16;

    float v[16];
    const float4* p = reinterpret_cast<const float4*>(s + (size_t)(r0 + r) * C + c0 + cg);
#pragma unroll
    for (int i = 0; i < 4; ++i) {
        float4 q = p[i];
        v[4 * i + 0] = q.x; v[4 * i + 1] = q.y; v[4 * i + 2] = q.z; v[4 * i + 3] = q.w;
    }
#pragma unroll
    for (int i = 0; i < 16; ++i) tile[r][cg + i] = v[i];

    if (dstS) {
        unsigned int w[8];
#pragma unroll
        for (int i = 0; i < 8; ++i)
            w[i] = (unsigned)f2bf(v[2 * i]) | ((unsigned)f2bf(v[2 * i + 1]) << 16);
        unsigned int* d = reinterpret_cast<unsigned int*>(
            dstS + (size_t)b * R * C + (size_t)(r0 + r) * C + c0 + cg);
        *reinterpret_cast<uint4*>(d)     = make_uint4(w[0], w[1], w[2], w[3]);
        *reinterpret_cast<uint4*>(d + 4) = make_uint4(w[4], w[5], w[6], w[7]);
    }

    __syncthreads();

    const int cl = t >> 2, rg = (t & 3) * 16;
    unsigned int w[8];
#pragma unroll
    for (int i = 0; i < 8; ++i) {
        unsigned short lo = f2bf(tile[rg + 2 * i][cl]);
        unsigned short hi = f2bf(tile[rg + 2 * i + 1][cl]);
        w[i] = (unsigned)lo | ((unsigned)hi << 16);
    }
    unsigned int* d = reinterpret_cast<unsigned int*>(
        dstT + (size_t)b * R * C + (size_t)(c0 + cl) * R + r0 + rg);
    *reinterpret_cast<uint4*>(d)     = make_uint4(w[0], w[1], w[2], w[3]);
    *reinterpret_cast<uint4*>(d + 4) = make_uint4(w[4], w[5], w[6], w[7]);
}

// ---------------------------------------------------------------------------
// kPre: H = F@W1 + bias (bf16 row-major) and G^T = (F@W2)^T (bf16
// [batch][256][2048]). Unchanged (passed; small).
// ---------------------------------------------------------------------------
__global__ __launch_bounds__(256, 2) void kpre_gemm(
    const float* __restrict__ F, const unsigned short* __restrict__ Wt,
    const float* __restrict__ bias, unsigned short* __restrict__ H,
    unsigned short* __restrict__ Gt)
{
    __shared__ __align__(16) short Fb[64 * 256];   // 32KB
    __shared__ __align__(16) short Wb[256 * 64];   // 32KB (+ G^T scratch)

    const int tid = threadIdx.x;
    const int lane = tid & 63, wid = tid >> 6;   // 4 waves
    const int lo = lane & 15, hi = lane >> 4;
    const int rb = blockIdx.x;                   // 0..511
    const int batch = rb >> 5;
    const int mb = (rb & 31) * 64;
    const size_t m0g = (size_t)rb * 64;

    {
        const int frow = tid >> 2, fq = tid & 3;
        const float* fp = F + (m0g + frow) * 256 + fq * 64;
#pragma unroll
        for (int g = 0; g < 2; ++g) {
            float4 q[8];
#pragma unroll
            for (int i = 0; i < 8; ++i)
                q[i] = reinterpret_cast<const float4*>(fp)[g * 8 + i];
#pragma unroll
            for (int j = 0; j < 4; ++j) {
                unsigned int w0 = pkbf(q[2*j].x,   q[2*j].y);
                unsigned int w1 = pkbf(q[2*j].z,   q[2*j].w);
                unsigned int w2 = pkbf(q[2*j+1].x, q[2*j+1].y);
                unsigned int w3 = pkbf(q[2*j+1].z, q[2*j+1].w);
                int slot = fq * 8 + g * 4 + j;
                int off = frow * 256 + ((slot ^ (frow & 7)) << 3);
                *reinterpret_cast<uint4*>(&Fb[off]) = make_uint4(w0, w1, w2, w3);
            }
        }
    }

    f32x4 acc[4][4];

#pragma unroll
    for (int pass = 0; pass < 2; ++pass) {
#pragma unroll
        for (int m = 0; m < 4; ++m)
#pragma unroll
            for (int n = 0; n < 4; ++n) acc[m][n] = (f32x4){0.f, 0.f, 0.f, 0.f};

        for (int kt = 0; kt < 4; ++kt) {
            const int kbase = pass * 256 + kt * 64;
#pragma unroll
            for (int it = 0; it < 8; ++it) {
                int si = it * 256 + tid;
                int row = si >> 3, slot = si & 7;
                const unsigned short* g = Wt + (size_t)row * 512 + kbase + ((slot ^ (row & 7)) << 3);
                gll16(g, Wb + (size_t)si * 8);
            }
            __syncthreads();

#pragma unroll
            for (int kk = 0; kk < 2; ++kk) {
                bf16x8 af[4], bw[4];
#pragma unroll
                for (int m = 0; m < 4; ++m) {
                    int row = m * 16 + lo;
                    int slot = kt * 8 + kk * 4 + hi;
                    af[m] = *reinterpret_cast<const bf16x8*>(&Fb[row * 256 + ((slot ^ (row & 7)) << 3)]);
                }
#pragma unroll
                for (int n = 0; n < 4; ++n) {
                    int row = wid * 64 + n * 16 + lo;
                    bw[n] = *reinterpret_cast<const bf16x8*>(&Wb[row * 64 + (((kk * 4 + hi) ^ (row & 7)) << 3)]);
                }
#pragma unroll
                for (int m = 0; m < 4; ++m)
#pragma unroll
                    for (int n = 0; n < 4; ++n)
                        acc[m][n] = __builtin_amdgcn_mfma_f32_16x16x32_bf16(af[m], bw[n], acc[m][n], 0, 0, 0);
            }
            __syncthreads();
        }

        if (pass == 0) {
            float bv[4];
#pragma unroll
            for (int n = 0; n < 4; ++n) bv[n] = bias[wid * 64 + n * 16 + lo];
            unsigned short* Hb = H + m0g * 256;
#pragma unroll
            for (int m = 0; m < 4; ++m)
#pragma unroll
                for (int n = 0; n < 4; ++n)
#pragma unroll
                    for (int j = 0; j < 4; ++j) {
                        int row = m * 16 + hi * 4 + j;
                        int col = wid * 64 + n * 16 + lo;
                        Hb[(size_t)row * 256 + col] = f2bf(acc[m][n][j] + bv[n]);
                    }
        } else {
            short* T = Wb + wid * 4096;
#pragma unroll
            for (int m = 0; m < 4; ++m)
#pragma unroll
                for (int n = 0; n < 4; ++n)
#pragma unroll
                    for (int j = 0; j < 4; ++j) {
                        int gr = m * 16 + hi * 4 + j;
                        int gc = n * 16 + lo;
                        int slot = gr >> 3, e = gr & 7;
                        T[gc * 64 + ((slot ^ (gc & 7)) << 3) + e] = f2bf(acc[m][n][j]);
                    }
            unsigned short* Gb = Gt + ((size_t)batch * 256 + wid * 64) * 2048 + mb;
#pragma unroll
            for (int i = 0; i < 8; ++i) {
                int f = i * 8 + (lane >> 3);
                int s = lane & 7;
                bf16x8 v = *reinterpret_cast<const bf16x8*>(&T[f * 64 + ((s ^ (f & 7)) << 3)]);
                *reinterpret_cast<bf16x8*>(Gb + (size_t)f * 2048 + s * 8) = v;
            }
        }
    }
}

// ---------------------------------------------------------------------------
// kconv_A: PROBE + producer. Pure grid-stride stream: A fp32 -> Abf bf16.
// Dense wave access: per instruction 64 lanes read 64 consecutive float4 =
// 1KB contiguous; 4 independent loads in flight per thread per iter.
// Its rocprof row measures the raw A-read rate in isolation.
// ---------------------------------------------------------------------------
__global__ __launch_bounds__(256) void kconv_A(
    const float* __restrict__ A, unsigned short* __restrict__ Abf, long long n4)
{
    const long long tid = (long long)blockIdx.x * 256 + threadIdx.x;
    const long long stride = (long long)gridDim.x * 256;   // in float4 units per j-slot
    // each iteration: 4 interleaved float4 loads (j*stride apart keeps every
    // wave instruction a dense 1KB read)
    for (long long base = tid; base < n4; base += stride * 4) {
        float4 q0, q1, q2, q3;
        long long i0 = base, i1 = base + stride, i2 = base + 2 * stride, i3 = base + 3 * stride;
        q0 = reinterpret_cast<const float4*>(A)[i0];
        if (i1 < n4) q1 = reinterpret_cast<const float4*>(A)[i1];
        if (i2 < n4) q2 = reinterpret_cast<const float4*>(A)[i2];
        if (i3 < n4) q3 = reinterpret_cast<const float4*>(A)[i3];
        uint2 w;
        w.x = pkbf(q0.x, q0.y); w.y = pkbf(q0.z, q0.w);
        reinterpret_cast<uint2*>(Abf)[i0] = w;
        if (i1 < n4) { w.x = pkbf(q1.x, q1.y); w.y = pkbf(q1.z, q1.w); reinterpret_cast<uint2*>(Abf)[i1] = w; }
        if (i2 < n4) { w.x = pkbf(q2.x, q2.y); w.y = pkbf(q2.z, q2.w); reinterpret_cast<uint2*>(Abf)[i2] = w; }
        if (i3 < n4) { w.x = pkbf(q3.x, q3.y); w.y = pkbf(q3.z, q3.w); reinterpret_cast<uint2*>(Abf)[i3] = w; }
    }
}

// ---------------------------------------------------------------------------
// kmain2: out = relu(H + A @ G), A now BF16 [b][2048][2048] from kconv_A.
// m97-proven 2-barrier dbuf structure: both operands via global_load_lds w=16
// (pre-swizzled source, linear LDS dest), ONE __syncthreads per body (its
// implicit vmcnt/lgkm drain retires tile t+1's glls), stage into the freed
// buffer right after the barrier (in flight across the whole next body).
// BM=128 BN=128 BK=64, 512 thr (8 waves 2x4, wave tile 64x32), 64KB LDS ->
// 2 blocks/CU (grid 512): cross-block overlap hides the barrier drain.
// ---------------------------------------------------------------------------
__global__ __launch_bounds__(512, 4) void kmain2_gemm(
    const unsigned short* __restrict__ Abf, const unsigned short* __restrict__ Gt,
    const unsigned short* __restrict__ H, float* __restrict__ out)
{
    __shared__ __align__(16) short Ab[2][128 * 64];   // 2 x 16KB
    __shared__ __align__(16) short Bb[2][128 * 64];   // 2 x 16KB

    const int tid = threadIdx.x;
    const int lane = tid & 63, wid = tid >> 6;
    const int wr = wid >> 2, wc = wid & 3;            // 2x4 -> wave tile 64x32
    const int lo = lane & 15, hi = lane >> 4;

    const int bid = blockIdx.x;
    const int wg = ((bid & 7) << 6) | (bid >> 3);     // bijective, 512 % 8 == 0
    const int batch = wg >> 5;
    const int mt    = (wg >> 1) & 15;
    const int nt    = wg & 1;

    const unsigned short* Abase = Abf + ((size_t)batch * 2048 + (size_t)mt * 128) * 2048;
    const unsigned short* Gbase = Gt + ((size_t)batch * 256 + (size_t)nt * 128) * 2048;

    f32x4 acc[4][2];
#pragma unroll
    for (int m = 0; m < 4; ++m)
#pragma unroll
        for (int n = 0; n < 2; ++n) acc[m][n] = (f32x4){0.f, 0.f, 0.f, 0.f};

    auto stage = [&](int buf, int k0) {
        // A tile: 128 rows x 8 slots (16B) = 1024 granules; 2 per thread
#pragma unroll
        for (int it = 0; it < 2; ++it) {
            int si = it * 512 + tid;
            int row = si >> 3, slot = si & 7;
            const unsigned short* g = Abase + (size_t)row * 2048 + k0 + ((slot ^ (row & 7)) << 3);
            gll16(g, &Ab[buf][(size_t)si * 8]);
        }
        // B tile: 128 rows x 8 slots = 1024 granules; 2 per thread
#pragma unroll
        for (int it = 0; it < 2; ++it) {
            int si = it * 512 + tid;
            int row = si >> 3, slot = si & 7;
            const unsigned short* g = Gbase + (size_t)row * 2048 + k0 + ((slot ^ (row & 7)) << 3);
            gll16(g, &Bb[buf][(size_t)si * 8]);
        }
    };
    auto compute = [&](int buf) {
#pragma unroll
        for (int kk = 0; kk < 2; ++kk) {
            bf16x8 af[4], bfv[2];
#pragma unroll
            for (int m = 0; m < 4; ++m) {
                int row = wr * 64 + m * 16 + lo;
                af[m] = *reinterpret_cast<const bf16x8*>(
                    &Ab[buf][row * 64 + (((kk * 4 + hi) ^ (row & 7)) << 3)]);
            }
#pragma unroll
            for (int n = 0; n < 2; ++n) {
                int row = wc * 32 + n * 16 + lo;
                bfv[n] = *reinterpret_cast<const bf16x8*>(
                    &Bb[buf][row * 64 + (((kk * 4 + hi) ^ (row & 7)) << 3)]);
            }
            __builtin_amdgcn_s_setprio(1);
#pragma unroll
            for (int m = 0; m < 4; ++m)
#pragma unroll
                for (int n = 0; n < 2; ++n)
                    acc[m][n] = __builtin_amdgcn_mfma_f32_16x16x32_bf16(af[m], bfv[n], acc[m][n], 0, 0, 0);
            __builtin_amdgcn_s_setprio(0);
        }
    };

    // prologue: tile0 -> buf0, drain, tile1 -> buf1 (lands during body 0)
    stage(0, 0);
    __syncthreads();
    stage(1, 64);

    for (int t = 0; t < 32; ++t) {
        compute(t & 1);
        __syncthreads();            // implicit full drain: gll(t+1) retired
        if (t + 2 < 32) stage(t & 1, (t + 2) * 64);
    }

    // epilogue: out = relu(acc + H)
    const size_t rowbase = (size_t)batch * 2048 + (size_t)mt * 128;
    const unsigned short* Hb = H + rowbase * 256;
    float* obase = out + rowbase * 256;
#pragma unroll
    for (int m = 0; m < 4; ++m) {
#pragma unroll
        for (int n = 0; n < 2; ++n) {
            int col = nt * 128 + wc * 32 + n * 16 + lo;
#pragma unroll
            for (int j = 0; j < 4; ++j) {
                int row = wr * 64 + m * 16 + hi * 4 + j;
                float v = acc[m][n][j] + bf2f(Hb[(size_t)row * 256 + col]);
                obase[(size_t)row * 256 + col] = fmaxf(v, 0.f);
            }
        }
    }
}

// ---------------------------------------------------------------------------
extern "C" void kernel_launch(void* const* d_in, const int* in_sizes, int n_in,
                              void* d_out, int out_size, void* d_ws, size_t ws_size,
                              hipStream_t stream) {
    const float* features = (const float*)d_in[0];   // [16][2048][256]
    const float* A        = (const float*)d_in[1];   // [16][2048][2048]
    const float* weight   = (const float*)d_in[2];   // [512][256]
    const float* bias     = (const float*)d_in[3];   // [256]
    float* out = (float*)d_out;

    const size_t WT_B  = (size_t)256 * 512 * 2;            // 256 KB
    const size_t H_B   = (size_t)32768 * 256 * 2;          // 16.78 MB
    const size_t GT_B  = (size_t)16 * 256 * 2048 * 2;      // 16.78 MB
    const size_t ABF_B = (size_t)16 * 2048 * 2048 * 2;     // 134.2 MB
    if (ws_size < WT_B + H_B + GT_B + ABF_B) return;

    char* ws = (char*)d_ws;
    unsigned short* Wt  = (unsigned short*)ws;
    unsigned short* H   = (unsigned short*)(ws + WT_B);
    unsigned short* Gt  = (unsigned short*)(ws + WT_B + H_B);
    unsigned short* Abf = (unsigned short*)(ws + WT_B + H_B + GT_B);

    dim3 gW(512 / 64, 256 / 64, 1);
    transpose_cvt_kernel<<<gW, 256, 0, stream>>>(weight, Wt, nullptr, 512, 256);

    kpre_gemm<<<512, 256, 0, stream>>>(features, Wt, bias, H, Gt);

    const long long n4 = (long long)16 * 2048 * 2048 / 4;  // float4 groups
    kconv_A<<<2048, 256, 0, stream>>>(A, Abf, n4);

    kmain2_gemm<<<512, 512, 0, stream>>>(Abf, Gt, H, out);
}

// Round 10
// 129.106 us; speedup vs baseline: 1.3611x; 1.3611x over previous
//
#include <hip/hip_runtime.h>

typedef __attribute__((ext_vector_type(8))) short bf16x8;
typedef __attribute__((ext_vector_type(4))) float f32x4;

// RNE bf16 (epilogues — off critical path)
__device__ __forceinline__ unsigned short f2bf(float f) {
    unsigned int u = __builtin_bit_cast(unsigned int, f);
    unsigned int r = (u + 0x7FFFu + ((u >> 16) & 1u)) >> 16;
    return (unsigned short)r;
}
// round-half-up pack of two fp32 -> packed bf16x2 (cheap) — staging hot path
__device__ __forceinline__ unsigned int pkbf(float lo, float hi) {
    unsigned int ul = __builtin_bit_cast(unsigned int, lo) + 0x8000u;
    unsigned int uh = __builtin_bit_cast(unsigned int, hi) + 0x8000u;
    return (uh & 0xFFFF0000u) | (ul >> 16);
}
__device__ __forceinline__ float bf2f(unsigned short u) {
    unsigned int x = ((unsigned int)u) << 16;
    return __builtin_bit_cast(float, x);
}

__device__ __forceinline__ void gll16(const void* g, void* l) {
    __builtin_amdgcn_global_load_lds(
        (const __attribute__((address_space(1))) void*)g,
        (__attribute__((address_space(3))) void*)l, 16, 0, 0);
}

// ---------------------------------------------------------------------------
// kW: tiled transpose + fp32->bf16. src [b][R][C] f32 -> dstT [b][C][R] bf16.
// ---------------------------------------------------------------------------
__global__ __launch_bounds__(256) void transpose_cvt_kernel(
    const float* __restrict__ src, unsigned short* __restrict__ dstT,
    unsigned short* __restrict__ dstS, int R, int C)
{
    __shared__ float tile[64][65];
    const int b = blockIdx.z;
    const float* s = src + (size_t)b * R * C;
    const int r0 = blockIdx.x * 64, c0 = blockIdx.y * 64;
    const int t = threadIdx.x;
    const int r = t >> 2, cg = (t & 3) * 16;

    float v[16];
    const float4* p = reinterpret_cast<const float4*>(s + (size_t)(r0 + r) * C + c0 + cg);
#pragma unroll
    for (int i = 0; i < 4; ++i) {
        float4 q = p[i];
        v[4 * i + 0] = q.x; v[4 * i + 1] = q.y; v[4 * i + 2] = q.z; v[4 * i + 3] = q.w;
    }
#pragma unroll
    for (int i = 0; i < 16; ++i) tile[r][cg + i] = v[i];

    if (dstS) {
        unsigned int w[8];
#pragma unroll
        for (int i = 0; i < 8; ++i)
            w[i] = (unsigned)f2bf(v[2 * i]) | ((unsigned)f2bf(v[2 * i + 1]) << 16);
        unsigned int* d = reinterpret_cast<unsigned int*>(
            dstS + (size_t)b * R * C + (size_t)(r0 + r) * C + c0 + cg);
        *reinterpret_cast<uint4*>(d)     = make_uint4(w[0], w[1], w[2], w[3]);
        *reinterpret_cast<uint4*>(d + 4) = make_uint4(w[4], w[5], w[6], w[7]);
    }

    __syncthreads();

    const int cl = t >> 2, rg = (t & 3) * 16;
    unsigned int w[8];
#pragma unroll
    for (int i = 0; i < 8; ++i) {
        unsigned short lo = f2bf(tile[rg + 2 * i][cl]);
        unsigned short hi = f2bf(tile[rg + 2 * i + 1][cl]);
        w[i] = (unsigned)lo | ((unsigned)hi << 16);
    }
    unsigned int* d = reinterpret_cast<unsigned int*>(
        dstT + (size_t)b * R * C + (size_t)(c0 + cl) * R + r0 + rg);
    *reinterpret_cast<uint4*>(d)     = make_uint4(w[0], w[1], w[2], w[3]);
    *reinterpret_cast<uint4*>(d + 4) = make_uint4(w[4], w[5], w[6], w[7]);
}

// ---------------------------------------------------------------------------
// kPre: H = F@W1 + bias (bf16 row-major) and G^T = (F@W2)^T (bf16
// [batch][256][2048]). Unchanged (passed; ~10 µs).
// ---------------------------------------------------------------------------
__global__ __launch_bounds__(256, 2) void kpre_gemm(
    const float* __restrict__ F, const unsigned short* __restrict__ Wt,
    const float* __restrict__ bias, unsigned short* __restrict__ H,
    unsigned short* __restrict__ Gt)
{
    __shared__ __align__(16) short Fb[64 * 256];   // 32KB
    __shared__ __align__(16) short Wb[256 * 64];   // 32KB (+ G^T scratch)

    const int tid = threadIdx.x;
    const int lane = tid & 63, wid = tid >> 6;   // 4 waves
    const int lo = lane & 15, hi = lane >> 4;
    const int rb = blockIdx.x;                   // 0..511
    const int batch = rb >> 5;
    const int mb = (rb & 31) * 64;
    const size_t m0g = (size_t)rb * 64;

    {
        const int frow = tid >> 2, fq = tid & 3;
        const float* fp = F + (m0g + frow) * 256 + fq * 64;
#pragma unroll
        for (int g = 0; g < 2; ++g) {
            float4 q[8];
#pragma unroll
            for (int i = 0; i < 8; ++i)
                q[i] = reinterpret_cast<const float4*>(fp)[g * 8 + i];
#pragma unroll
            for (int j = 0; j < 4; ++j) {
                unsigned int w0 = pkbf(q[2*j].x,   q[2*j].y);
                unsigned int w1 = pkbf(q[2*j].z,   q[2*j].w);
                unsigned int w2 = pkbf(q[2*j+1].x, q[2*j+1].y);
                unsigned int w3 = pkbf(q[2*j+1].z, q[2*j+1].w);
                int slot = fq * 8 + g * 4 + j;
                int off = frow * 256 + ((slot ^ (frow & 7)) << 3);
                *reinterpret_cast<uint4*>(&Fb[off]) = make_uint4(w0, w1, w2, w3);
            }
        }
    }

    f32x4 acc[4][4];

#pragma unroll
    for (int pass = 0; pass < 2; ++pass) {
#pragma unroll
        for (int m = 0; m < 4; ++m)
#pragma unroll
            for (int n = 0; n < 4; ++n) acc[m][n] = (f32x4){0.f, 0.f, 0.f, 0.f};

        for (int kt = 0; kt < 4; ++kt) {
            const int kbase = pass * 256 + kt * 64;
#pragma unroll
            for (int it = 0; it < 8; ++it) {
                int si = it * 256 + tid;
                int row = si >> 3, slot = si & 7;
                const unsigned short* g = Wt + (size_t)row * 512 + kbase + ((slot ^ (row & 7)) << 3);
                gll16(g, Wb + (size_t)si * 8);
            }
            __syncthreads();

#pragma unroll
            for (int kk = 0; kk < 2; ++kk) {
                bf16x8 af[4], bw[4];
#pragma unroll
                for (int m = 0; m < 4; ++m) {
                    int row = m * 16 + lo;
                    int slot = kt * 8 + kk * 4 + hi;
                    af[m] = *reinterpret_cast<const bf16x8*>(&Fb[row * 256 + ((slot ^ (row & 7)) << 3)]);
                }
#pragma unroll
                for (int n = 0; n < 4; ++n) {
                    int row = wid * 64 + n * 16 + lo;
                    bw[n] = *reinterpret_cast<const bf16x8*>(&Wb[row * 64 + (((kk * 4 + hi) ^ (row & 7)) << 3)]);
                }
#pragma unroll
                for (int m = 0; m < 4; ++m)
#pragma unroll
                    for (int n = 0; n < 4; ++n)
                        acc[m][n] = __builtin_amdgcn_mfma_f32_16x16x32_bf16(af[m], bw[n], acc[m][n], 0, 0, 0);
            }
            __syncthreads();
        }

        if (pass == 0) {
            float bv[4];
#pragma unroll
            for (int n = 0; n < 4; ++n) bv[n] = bias[wid * 64 + n * 16 + lo];
            unsigned short* Hb = H + m0g * 256;
#pragma unroll
            for (int m = 0; m < 4; ++m)
#pragma unroll
                for (int n = 0; n < 4; ++n)
#pragma unroll
                    for (int j = 0; j < 4; ++j) {
                        int row = m * 16 + hi * 4 + j;
                        int col = wid * 64 + n * 16 + lo;
                        Hb[(size_t)row * 256 + col] = f2bf(acc[m][n][j] + bv[n]);
                    }
        } else {
            short* T = Wb + wid * 4096;
#pragma unroll
            for (int m = 0; m < 4; ++m)
#pragma unroll
                for (int n = 0; n < 4; ++n)
#pragma unroll
                    for (int j = 0; j < 4; ++j) {
                        int gr = m * 16 + hi * 4 + j;
                        int gc = n * 16 + lo;
                        int slot = gr >> 3, e = gr & 7;
                        T[gc * 64 + ((slot ^ (gc & 7)) << 3) + e] = f2bf(acc[m][n][j]);
                    }
            unsigned short* Gb = Gt + ((size_t)batch * 256 + wid * 64) * 2048 + mb;
#pragma unroll
            for (int i = 0; i < 8; ++i) {
                int f = i * 8 + (lane >> 3);
                int s = lane & 7;
                bf16x8 v = *reinterpret_cast<const bf16x8*>(&T[f * 64 + ((s ^ (f & 7)) << 3)]);
                *reinterpret_cast<bf16x8*>(Gb + (size_t)f * 2048 + s * 8) = v;
            }
        }
    }
}

// ---------------------------------------------------------------------------
// kMain (R10): P[ks] = A[:, ksK:+1024] @ G — m97-faithful high-TLP form.
// 256 threads (4 waves 1x4, wave tile 64x64), BM=64 BN=256 BK=64,
// SINGLE-buffered 40KB LDS -> 4 blocks/CU resident (launch_bounds(256,4)
// caps VGPR at 128); grid = 16b x 32mt x 2ks = 1024 blocks = 4/CU. Cross-
// block wave overlap hides the barrier drains (m114/m102 mechanism: the
// shape curve 320->833 TF is the 1->4 blocks/CU curve).
// Split-K halves are disjoint -> A still read exactly once (268 MB).
// Per K-step: loadA(t+1) regs -> compute(t) -> bar -> gll B(t+1) + packA -> bar.
// XCD swizzle: each XCD owns 2 whole batches; consecutive blocks share the
// same 512KB Gt half-panel (L2-hot).
// ---------------------------------------------------------------------------
__global__ __launch_bounds__(256, 4) void kmain_gemm(
    const float* __restrict__ A, const unsigned short* __restrict__ Gt,
    unsigned short* __restrict__ P)
{
    __shared__ __align__(16) short Ab[64 * 64];    // 8 KB
    __shared__ __align__(16) short Bb[256 * 64];   // 32 KB

    const int tid = threadIdx.x;
    const int lane = tid & 63, wid = tid >> 6;     // 4 waves, 1x4
    const int lo = lane & 15, hi = lane >> 4;

    const int bid = blockIdx.x;
    const int wg = ((bid & 7) << 7) | (bid >> 3);  // bijective, 1024 % 8 == 0
    const int batch = wg >> 6;                     // 2 batches per XCD
    const int ks    = (wg >> 5) & 1;
    const int mt    = wg & 31;

    const float* Abase = A + ((size_t)batch * 2048 + (size_t)mt * 64) * 2048 + ks * 1024;
    const unsigned short* Gbase = Gt + (size_t)batch * 256 * 2048 + ks * 1024;

    const int arow = tid >> 2;     // 0..63
    const int aq   = tid & 3;      // 16-float col group (64B -> one full sector/4 lanes)

    f32x4 acc[4][4];
#pragma unroll
    for (int m = 0; m < 4; ++m)
#pragma unroll
        for (int n = 0; n < 4; ++n) acc[m][n] = (f32x4){0.f, 0.f, 0.f, 0.f};

    float4 qa[4];
    auto loadA = [&](int k0) {
        const float4* p = reinterpret_cast<const float4*>(
            Abase + (size_t)arow * 2048 + k0 + aq * 16);
#pragma unroll
        for (int i = 0; i < 4; ++i) qa[i] = p[i];
    };
    auto writeA = [&]() {
#pragma unroll
        for (int j = 0; j < 2; ++j) {
            uint4 w;
            w.x = pkbf(qa[2*j].x,   qa[2*j].y);
            w.y = pkbf(qa[2*j].z,   qa[2*j].w);
            w.z = pkbf(qa[2*j+1].x, qa[2*j+1].y);
            w.w = pkbf(qa[2*j+1].z, qa[2*j+1].w);
            int slin = aq * 2 + j;
            int off = arow * 64 + ((slin ^ (arow & 7)) << 3);
            *reinterpret_cast<uint4*>(&Ab[off]) = w;
        }
    };
    auto stageB = [&](int k0) {
#pragma unroll
        for (int it = 0; it < 8; ++it) {
            int si = it * 256 + tid;
            int row = si >> 3, slot = si & 7;
            const unsigned short* g = Gbase + (size_t)row * 2048 + k0 + ((slot ^ (row & 7)) << 3);
            gll16(g, &Bb[(size_t)si * 8]);
        }
    };
    auto compute = [&]() {
#pragma unroll
        for (int kk = 0; kk < 2; ++kk) {
            bf16x8 af[4], bfv[4];
#pragma unroll
            for (int m = 0; m < 4; ++m) {
                int row = m * 16 + lo;
                af[m] = *reinterpret_cast<const bf16x8*>(
                    &Ab[row * 64 + (((kk * 4 + hi) ^ (row & 7)) << 3)]);
            }
#pragma unroll
            for (int n = 0; n < 4; ++n) {
                int row = wid * 64 + n * 16 + lo;
                bfv[n] = *reinterpret_cast<const bf16x8*>(
                    &Bb[row * 64 + (((kk * 4 + hi) ^ (row & 7)) << 3)]);
            }
            __builtin_amdgcn_s_setprio(1);
#pragma unroll
            for (int m = 0; m < 4; ++m)
#pragma unroll
                for (int n = 0; n < 4; ++n)
                    acc[m][n] = __builtin_amdgcn_mfma_f32_16x16x32_bf16(af[m], bfv[n], acc[m][n], 0, 0, 0);
            __builtin_amdgcn_s_setprio(0);
        }
    };

    // prologue
    loadA(0);
    stageB(0);
    writeA();            // compiler waits A-loads only (gll newer in vm queue)
    __syncthreads();     // drains gll(0) + ds_writes

    for (int t = 0; t < 16; ++t) {
        if (t + 1 < 16) loadA((t + 1) * 64);   // fp32 latency hides under compute
        compute();
        __syncthreads();                       // all LDS reads of tile t done
        if (t + 1 < 16) {
            stageB((t + 1) * 64);              // gll; other blocks cover the wait
            writeA();
            __syncthreads();                   // tile t+1 ready
        }
    }

    // epilogue -> bf16 partials
    unsigned short* Pb = P + ((size_t)ks * 32768 + (size_t)batch * 2048 + (size_t)mt * 64) * 256;
#pragma unroll
    for (int m = 0; m < 4; ++m) {
#pragma unroll
        for (int n = 0; n < 4; ++n) {
            int col = wid * 64 + n * 16 + lo;
#pragma unroll
            for (int j = 0; j < 4; ++j) {
                int row = m * 16 + hi * 4 + j;
                Pb[(size_t)row * 256 + col] = f2bf(acc[m][n][j]);
            }
        }
    }
}

// ---------------------------------------------------------------------------
// kRed: out = relu(P0 + P1 + H), all bf16 -> fp32. Pure stream, bf16x8 loads.
// ---------------------------------------------------------------------------
__global__ __launch_bounds__(256) void kred_kernel(
    const unsigned short* __restrict__ P, const unsigned short* __restrict__ H,
    float* __restrict__ out)
{
    const long long n8 = (long long)32768 * 256 / 8;     // 1048576 groups
    const long long p1 = (long long)32768 * 256;
    long long i = (long long)blockIdx.x * 256 + threadIdx.x;
    const long long stride = (long long)gridDim.x * 256;
    for (; i < n8; i += stride) {
        bf16x8 a = *reinterpret_cast<const bf16x8*>(&P[i * 8]);
        bf16x8 b = *reinterpret_cast<const bf16x8*>(&P[p1 + i * 8]);
        bf16x8 h = *reinterpret_cast<const bf16x8*>(&H[i * 8]);
        float4 o0, o1;
        float v;
        v = bf2f((unsigned short)a[0]) + bf2f((unsigned short)b[0]) + bf2f((unsigned short)h[0]); o0.x = fmaxf(v, 0.f);
        v = bf2f((unsigned short)a[1]) + bf2f((unsigned short)b[1]) + bf2f((unsigned short)h[1]); o0.y = fmaxf(v, 0.f);
        v = bf2f((unsigned short)a[2]) + bf2f((unsigned short)b[2]) + bf2f((unsigned short)h[2]); o0.z = fmaxf(v, 0.f);
        v = bf2f((unsigned short)a[3]) + bf2f((unsigned short)b[3]) + bf2f((unsigned short)h[3]); o0.w = fmaxf(v, 0.f);
        v = bf2f((unsigned short)a[4]) + bf2f((unsigned short)b[4]) + bf2f((unsigned short)h[4]); o1.x = fmaxf(v, 0.f);
        v = bf2f((unsigned short)a[5]) + bf2f((unsigned short)b[5]) + bf2f((unsigned short)h[5]); o1.y = fmaxf(v, 0.f);
        v = bf2f((unsigned short)a[6]) + bf2f((unsigned short)b[6]) + bf2f((unsigned short)h[6]); o1.z = fmaxf(v, 0.f);
        v = bf2f((unsigned short)a[7]) + bf2f((unsigned short)b[7]) + bf2f((unsigned short)h[7]); o1.w = fmaxf(v, 0.f);
        reinterpret_cast<float4*>(out + i * 8)[0] = o0;
        reinterpret_cast<float4*>(out + i * 8)[1] = o1;
    }
}

// ---------------------------------------------------------------------------
extern "C" void kernel_launch(void* const* d_in, const int* in_sizes, int n_in,
                              void* d_out, int out_size, void* d_ws, size_t ws_size,
                              hipStream_t stream) {
    const float* features = (const float*)d_in[0];   // [16][2048][256]
    const float* A        = (const float*)d_in[1];   // [16][2048][2048]
    const float* weight   = (const float*)d_in[2];   // [512][256]
    const float* bias     = (const float*)d_in[3];   // [256]
    float* out = (float*)d_out;

    const size_t WT_B = (size_t)256 * 512 * 2;             // 256 KB
    const size_t H_B  = (size_t)32768 * 256 * 2;           // 16.78 MB
    const size_t GT_B = (size_t)16 * 256 * 2048 * 2;       // 16.78 MB
    const size_t P_B  = (size_t)2 * 32768 * 256 * 2;       // 33.55 MB
    if (ws_size < WT_B + H_B + GT_B + P_B) return;

    char* ws = (char*)d_ws;
    unsigned short* Wt = (unsigned short*)ws;
    unsigned short* H  = (unsigned short*)(ws + WT_B);
    unsigned short* Gt = (unsigned short*)(ws + WT_B + H_B);
    unsigned short* P  = (unsigned short*)(ws + WT_B + H_B + GT_B);

    dim3 gW(512 / 64, 256 / 64, 1);
    transpose_cvt_kernel<<<gW, 256, 0, stream>>>(weight, Wt, nullptr, 512, 256);

    kpre_gemm<<<512, 256, 0, stream>>>(features, Wt, bias, H, Gt);

    kmain_gemm<<<1024, 256, 0, stream>>>(A, Gt, P);

    kred_kernel<<<2048, 256, 0, stream>>>(P, H, out);
}

// Round 11
// 128.081 us; speedup vs baseline: 1.3720x; 1.0080x over previous
//
#include <hip/hip_runtime.h>

typedef __attribute__((ext_vector_type(8))) short bf16x8;
typedef __attribute__((ext_vector_type(4))) float f32x4;

// RNE bf16 (epilogues — off critical path)
__device__ __forceinline__ unsigned short f2bf(float f) {
    unsigned int u = __builtin_bit_cast(unsigned int, f);
    unsigned int r = (u + 0x7FFFu + ((u >> 16) & 1u)) >> 16;
    return (unsigned short)r;
}
// round-half-up pack of two fp32 -> packed bf16x2 (cheap) — staging hot path
__device__ __forceinline__ unsigned int pkbf(float lo, float hi) {
    unsigned int ul = __builtin_bit_cast(unsigned int, lo) + 0x8000u;
    unsigned int uh = __builtin_bit_cast(unsigned int, hi) + 0x8000u;
    return (uh & 0xFFFF0000u) | (ul >> 16);
}
__device__ __forceinline__ float bf2f(unsigned short u) {
    unsigned int x = ((unsigned int)u) << 16;
    return __builtin_bit_cast(float, x);
}

__device__ __forceinline__ void gll16(const void* g, void* l) {
    __builtin_amdgcn_global_load_lds(
        (const __attribute__((address_space(1))) void*)g,
        (__attribute__((address_space(3))) void*)l, 16, 0, 0);
}

// ---------------------------------------------------------------------------
// kW: tiled transpose + fp32->bf16. src [b][R][C] f32 -> dstT [b][C][R] bf16.
// ---------------------------------------------------------------------------
__global__ __launch_bounds__(256) void transpose_cvt_kernel(
    const float* __restrict__ src, unsigned short* __restrict__ dstT,
    unsigned short* __restrict__ dstS, int R, int C)
{
    __shared__ float tile[64][65];
    const int b = blockIdx.z;
    const float* s = src + (size_t)b * R * C;
    const int r0 = blockIdx.x * 64, c0 = blockIdx.y * 64;
    const int t = threadIdx.x;
    const int r = t >> 2, cg = (t & 3) * 16;

    float v[16];
    const float4* p = reinterpret_cast<const float4*>(s + (size_t)(r0 + r) * C + c0 + cg);
#pragma unroll
    for (int i = 0; i < 4; ++i) {
        float4 q = p[i];
        v[4 * i + 0] = q.x; v[4 * i + 1] = q.y; v[4 * i + 2] = q.z; v[4 * i + 3] = q.w;
    }
#pragma unroll
    for (int i = 0; i < 16; ++i) tile[r][cg + i] = v[i];

    if (dstS) {
        unsigned int w[8];
#pragma unroll
        for (int i = 0; i < 8; ++i)
            w[i] = (unsigned)f2bf(v[2 * i]) | ((unsigned)f2bf(v[2 * i + 1]) << 16);
        unsigned int* d = reinterpret_cast<unsigned int*>(
            dstS + (size_t)b * R * C + (size_t)(r0 + r) * C + c0 + cg);
        *reinterpret_cast<uint4*>(d)     = make_uint4(w[0], w[1], w[2], w[3]);
        *reinterpret_cast<uint4*>(d + 4) = make_uint4(w[4], w[5], w[6], w[7]);
    }

    __syncthreads();

    const int cl = t >> 2, rg = (t & 3) * 16;
    unsigned int w[8];
#pragma unroll
    for (int i = 0; i < 8; ++i) {
        unsigned short lo = f2bf(tile[rg + 2 * i][cl]);
        unsigned short hi = f2bf(tile[rg + 2 * i + 1][cl]);
        w[i] = (unsigned)lo | ((unsigned)hi << 16);
    }
    unsigned int* d = reinterpret_cast<unsigned int*>(
        dstT + (size_t)b * R * C + (size_t)(c0 + cl) * R + r0 + rg);
    *reinterpret_cast<uint4*>(d)     = make_uint4(w[0], w[1], w[2], w[3]);
    *reinterpret_cast<uint4*>(d + 4) = make_uint4(w[4], w[5], w[6], w[7]);
}

// ---------------------------------------------------------------------------
// kPre: H = F@W1 + bias (bf16 row-major) and G^T = (F@W2)^T (bf16
// [batch][256][2048]). Unchanged (passed; ~10 µs).
// ---------------------------------------------------------------------------
__global__ __launch_bounds__(256, 2) void kpre_gemm(
    const float* __restrict__ F, const unsigned short* __restrict__ Wt,
    const float* __restrict__ bias, unsigned short* __restrict__ H,
    unsigned short* __restrict__ Gt)
{
    __shared__ __align__(16) short Fb[64 * 256];   // 32KB
    __shared__ __align__(16) short Wb[256 * 64];   // 32KB (+ G^T scratch)

    const int tid = threadIdx.x;
    const int lane = tid & 63, wid = tid >> 6;   // 4 waves
    const int lo = lane & 15, hi = lane >> 4;
    const int rb = blockIdx.x;                   // 0..511
    const int batch = rb >> 5;
    const int mb = (rb & 31) * 64;
    const size_t m0g = (size_t)rb * 64;

    {
        const int frow = tid >> 2, fq = tid & 3;
        const float* fp = F + (m0g + frow) * 256 + fq * 64;
#pragma unroll
        for (int g = 0; g < 2; ++g) {
            float4 q[8];
#pragma unroll
            for (int i = 0; i < 8; ++i)
                q[i] = reinterpret_cast<const float4*>(fp)[g * 8 + i];
#pragma unroll
            for (int j = 0; j < 4; ++j) {
                unsigned int w0 = pkbf(q[2*j].x,   q[2*j].y);
                unsigned int w1 = pkbf(q[2*j].z,   q[2*j].w);
                unsigned int w2 = pkbf(q[2*j+1].x, q[2*j+1].y);
                unsigned int w3 = pkbf(q[2*j+1].z, q[2*j+1].w);
                int slot = fq * 8 + g * 4 + j;
                int off = frow * 256 + ((slot ^ (frow & 7)) << 3);
                *reinterpret_cast<uint4*>(&Fb[off]) = make_uint4(w0, w1, w2, w3);
            }
        }
    }

    f32x4 acc[4][4];

#pragma unroll
    for (int pass = 0; pass < 2; ++pass) {
#pragma unroll
        for (int m = 0; m < 4; ++m)
#pragma unroll
            for (int n = 0; n < 4; ++n) acc[m][n] = (f32x4){0.f, 0.f, 0.f, 0.f};

        for (int kt = 0; kt < 4; ++kt) {
            const int kbase = pass * 256 + kt * 64;
#pragma unroll
            for (int it = 0; it < 8; ++it) {
                int si = it * 256 + tid;
                int row = si >> 3, slot = si & 7;
                const unsigned short* g = Wt + (size_t)row * 512 + kbase + ((slot ^ (row & 7)) << 3);
                gll16(g, Wb + (size_t)si * 8);
            }
            __syncthreads();

#pragma unroll
            for (int kk = 0; kk < 2; ++kk) {
                bf16x8 af[4], bw[4];
#pragma unroll
                for (int m = 0; m < 4; ++m) {
                    int row = m * 16 + lo;
                    int slot = kt * 8 + kk * 4 + hi;
                    af[m] = *reinterpret_cast<const bf16x8*>(&Fb[row * 256 + ((slot ^ (row & 7)) << 3)]);
                }
#pragma unroll
                for (int n = 0; n < 4; ++n) {
                    int row = wid * 64 + n * 16 + lo;
                    bw[n] = *reinterpret_cast<const bf16x8*>(&Wb[row * 64 + (((kk * 4 + hi) ^ (row & 7)) << 3)]);
                }
#pragma unroll
                for (int m = 0; m < 4; ++m)
#pragma unroll
                    for (int n = 0; n < 4; ++n)
                        acc[m][n] = __builtin_amdgcn_mfma_f32_16x16x32_bf16(af[m], bw[n], acc[m][n], 0, 0, 0);
            }
            __syncthreads();
        }

        if (pass == 0) {
            float bv[4];
#pragma unroll
            for (int n = 0; n < 4; ++n) bv[n] = bias[wid * 64 + n * 16 + lo];
            unsigned short* Hb = H + m0g * 256;
#pragma unroll
            for (int m = 0; m < 4; ++m)
#pragma unroll
                for (int n = 0; n < 4; ++n)
#pragma unroll
                    for (int j = 0; j < 4; ++j) {
                        int row = m * 16 + hi * 4 + j;
                        int col = wid * 64 + n * 16 + lo;
                        Hb[(size_t)row * 256 + col] = f2bf(acc[m][n][j] + bv[n]);
                    }
        } else {
            short* T = Wb + wid * 4096;
#pragma unroll
            for (int m = 0; m < 4; ++m)
#pragma unroll
                for (int n = 0; n < 4; ++n)
#pragma unroll
                    for (int j = 0; j < 4; ++j) {
                        int gr = m * 16 + hi * 4 + j;
                        int gc = n * 16 + lo;
                        int slot = gr >> 3, e = gr & 7;
                        T[gc * 64 + ((slot ^ (gc & 7)) << 3) + e] = f2bf(acc[m][n][j]);
                    }
            unsigned short* Gb = Gt + ((size_t)batch * 256 + wid * 64) * 2048 + mb;
#pragma unroll
            for (int i = 0; i < 8; ++i) {
                int f = i * 8 + (lane >> 3);
                int s = lane & 7;
                bf16x8 v = *reinterpret_cast<const bf16x8*>(&T[f * 64 + ((s ^ (f & 7)) << 3)]);
                *reinterpret_cast<bf16x8*>(Gb + (size_t)f * 2048 + s * 8) = v;
            }
        }
    }
}

// ---------------------------------------------------------------------------
// kMain (R11): out = relu(H + A @ G) — clean 4-blocks/CU TLP test.
// 256 thr (4 waves 1x4), wave tile 64x32 -> BM=64 BN=128. acc[4][2]=32 VGPR,
// total ~100 VGPR (no launch_bounds cap -> no spill), LDS 24KB single-buf.
// Grid = 16b x 32mt x 2nt = 1024 blocks = 4/CU resident, 16 waves/CU —
// the m102 curve's 833-TF operating point (m97-identical block, more blocks).
// NO split-K, NO reduction kernel. nt-pair shares A rows; XCD swizzle puts
// the pair on the same XCD adjacent in dispatch -> 2nd read L2-hot.
// 2-barrier m97 body: loadA(t+1) -> compute(t) -> bar -> gll B(t+1)+packA -> bar.
// ---------------------------------------------------------------------------
__global__ __launch_bounds__(256) void kmain_gemm(
    const float* __restrict__ A, const unsigned short* __restrict__ Gt,
    const unsigned short* __restrict__ H, float* __restrict__ out)
{
    __shared__ __align__(16) short Ab[64 * 64];    // 8 KB
    __shared__ __align__(16) short Bb[128 * 64];   // 16 KB

    const int tid = threadIdx.x;
    const int lane = tid & 63, wid = tid >> 6;     // 4 waves, 1x4 over BN
    const int lo = lane & 15, hi = lane >> 4;

    const int bid = blockIdx.x;
    const int wg = ((bid & 7) << 7) | (bid >> 3);  // bijective, 1024 % 8 == 0
    const int batch = wg >> 6;                     // 2 batches per XCD
    const int mt    = (wg >> 1) & 31;
    const int nt    = wg & 1;

    const float* Abase = A + ((size_t)batch * 2048 + (size_t)mt * 64) * 2048;
    const unsigned short* Gbase = Gt + ((size_t)batch * 256 + (size_t)nt * 128) * 2048;

    const int arow = tid >> 2;     // 0..63
    const int aq   = tid & 3;      // 16-float col group

    f32x4 acc[4][2];
#pragma unroll
    for (int m = 0; m < 4; ++m)
#pragma unroll
        for (int n = 0; n < 2; ++n) acc[m][n] = (f32x4){0.f, 0.f, 0.f, 0.f};

    float4 qa[4];
    auto loadA = [&](int k0) {
        const float4* p = reinterpret_cast<const float4*>(
            Abase + (size_t)arow * 2048 + k0 + aq * 16);
#pragma unroll
        for (int i = 0; i < 4; ++i) qa[i] = p[i];
    };
    auto writeA = [&]() {
#pragma unroll
        for (int j = 0; j < 2; ++j) {
            uint4 w;
            w.x = pkbf(qa[2*j].x,   qa[2*j].y);
            w.y = pkbf(qa[2*j].z,   qa[2*j].w);
            w.z = pkbf(qa[2*j+1].x, qa[2*j+1].y);
            w.w = pkbf(qa[2*j+1].z, qa[2*j+1].w);
            int slin = aq * 2 + j;
            int off = arow * 64 + ((slin ^ (arow & 7)) << 3);
            *reinterpret_cast<uint4*>(&Ab[off]) = w;
        }
    };
    auto stageB = [&](int k0) {
#pragma unroll
        for (int it = 0; it < 4; ++it) {
            int si = it * 256 + tid;
            int row = si >> 3, slot = si & 7;
            const unsigned short* g = Gbase + (size_t)row * 2048 + k0 + ((slot ^ (row & 7)) << 3);
            gll16(g, &Bb[(size_t)si * 8]);
        }
    };
    auto compute = [&]() {
#pragma unroll
        for (int kk = 0; kk < 2; ++kk) {
            bf16x8 af[4], bfv[2];
#pragma unroll
            for (int m = 0; m < 4; ++m) {
                int row = m * 16 + lo;
                af[m] = *reinterpret_cast<const bf16x8*>(
                    &Ab[row * 64 + (((kk * 4 + hi) ^ (row & 7)) << 3)]);
            }
#pragma unroll
            for (int n = 0; n < 2; ++n) {
                int row = wid * 32 + n * 16 + lo;
                bfv[n] = *reinterpret_cast<const bf16x8*>(
                    &Bb[row * 64 + (((kk * 4 + hi) ^ (row & 7)) << 3)]);
            }
            __builtin_amdgcn_s_setprio(1);
#pragma unroll
            for (int m = 0; m < 4; ++m)
#pragma unroll
                for (int n = 0; n < 2; ++n)
                    acc[m][n] = __builtin_amdgcn_mfma_f32_16x16x32_bf16(af[m], bfv[n], acc[m][n], 0, 0, 0);
            __builtin_amdgcn_s_setprio(0);
        }
    };

    // prologue
    loadA(0);
    stageB(0);
    writeA();            // waits A(0) loads (older than gll in vm queue)
    __syncthreads();     // drains gll(0) + ds_writes

    for (int t = 0; t < 32; ++t) {
        if (t + 1 < 32) loadA((t + 1) * 64);   // fp32 latency hides under compute
        compute();
        __syncthreads();                       // LDS reads of tile t done (+A loads forced)
        if (t + 1 < 32) {
            stageB((t + 1) * 64);              // gll; 3 sibling blocks cover the wait
            writeA();
            __syncthreads();                   // tile t+1 ready
        }
    }

    // epilogue: out = relu(acc + H)
    const size_t rowbase = (size_t)batch * 2048 + (size_t)mt * 64;
    const unsigned short* Hb = H + rowbase * 256;
    float* obase = out + rowbase * 256;
#pragma unroll
    for (int m = 0; m < 4; ++m) {
#pragma unroll
        for (int n = 0; n < 2; ++n) {
            int col = nt * 128 + wid * 32 + n * 16 + lo;
#pragma unroll
            for (int j = 0; j < 4; ++j) {
                int row = m * 16 + hi * 4 + j;
                float v = acc[m][n][j] + bf2f(Hb[(size_t)row * 256 + col]);
                obase[(size_t)row * 256 + col] = fmaxf(v, 0.f);
            }
        }
    }
}

// ---------------------------------------------------------------------------
extern "C" void kernel_launch(void* const* d_in, const int* in_sizes, int n_in,
                              void* d_out, int out_size, void* d_ws, size_t ws_size,
                              hipStream_t stream) {
    const float* features = (const float*)d_in[0];   // [16][2048][256]
    const float* A        = (const float*)d_in[1];   // [16][2048][2048]
    const float* weight   = (const float*)d_in[2];   // [512][256]
    const float* bias     = (const float*)d_in[3];   // [256]
    float* out = (float*)d_out;

    const size_t WT_B = (size_t)256 * 512 * 2;             // 256 KB
    const size_t H_B  = (size_t)32768 * 256 * 2;           // 16.78 MB
    const size_t GT_B = (size_t)16 * 256 * 2048 * 2;       // 16.78 MB
    if (ws_size < WT_B + H_B + GT_B) return;

    char* ws = (char*)d_ws;
    unsigned short* Wt = (unsigned short*)ws;
    unsigned short* H  = (unsigned short*)(ws + WT_B);
    unsigned short* Gt = (unsigned short*)(ws + WT_B + H_B);

    dim3 gW(512 / 64, 256 / 64, 1);
    transpose_cvt_kernel<<<gW, 256, 0, stream>>>(weight, Wt, nullptr, 512, 256);

    kpre_gemm<<<512, 256, 0, stream>>>(features, Wt, bias, H, Gt);

    kmain_gemm<<<1024, 256, 0, stream>>>(A, Gt, H, out);
}